// Round 6
// baseline (421.278 us; speedup 1.0000x reference)
//
#include <hip/hip_runtime.h>
#include <stdint.h>

#define B_ 256
#define N_ 256
#define F_ 64
#define H_ 512

typedef _Float16 f16;
typedef _Float16 f16x8 __attribute__((ext_vector_type(8)));
typedef _Float16 f16x4 __attribute__((ext_vector_type(4)));
typedef _Float16 f16x2 __attribute__((ext_vector_type(2)));
typedef float    f32x4 __attribute__((ext_vector_type(4)));

__device__ __forceinline__ float sigmoidf_(float x) {
    return 1.0f / (1.0f + __expf(-x));
}

// Counted-vmcnt barrier pair (T3/T4 pattern):
// ACQ(N): wait until <=N VMEM ops outstanding (the N newest = next tile's
// loads stay in flight), then barrier. sched_barrier(0) fences MFMA hoisting
// past the waitcnt (rule #18).
#define BAR_ACQ(N) do { \
    asm volatile("s_waitcnt vmcnt(" #N ")" ::: "memory"); \
    __builtin_amdgcn_s_barrier(); \
    __builtin_amdgcn_sched_barrier(0); } while (0)
#define BAR_REL() do { \
    __builtin_amdgcn_sched_barrier(0); \
    __builtin_amdgcn_s_barrier(); } while (0)

// Direct global->VGPR fragment load (asm volatile: cannot be sunk by the
// compiler -- round 2's plain-load version was sunk to the use point).
// Data is valid only after a vmcnt wait; consumption is gated by BAR_ACQ.
#define GLOADX4(dst, ptr, IMM) \
    asm volatile("global_load_dwordx4 %0, %1, off offset:" #IMM \
                 : "=v"(dst) : "v"(ptr) : "memory")

// ---------------------------------------------------------------------------
// k_fsum: fused sigmoid + symmetrize + degree-normalize, one block per batch.
// S = sigmoid(z_b) lives ONLY in LDS (256 x LD f16); row sums via shuffle,
// col sums via per-lane partials + cross-wave LDS reduce; then
// nA[i,j] = (0.5*(S_ij+S_ji)+delta_ij)*Di*Dj emitted straight to global.
// LD=258: rows are 516 B (4B-aligned only!) -> all LDS accesses to T <=4B.
__global__ __launch_bounds__(512) void k_fsum(const float* __restrict__ z,
                                              f16* __restrict__ nA) {
    constexpr int LD = 258;
    __shared__ f16 T[256 * LD];          // 132,096 B
    __shared__ float cpart[8][256];      // 8 KB
    __shared__ float rbuf[256];
    __shared__ float Dv[256];

    const int b = blockIdx.x;
    const int tid = threadIdx.x, lane = tid & 63, w = tid >> 6;
    const float* zb = z + (size_t)b * (N_ * N_);

    float colacc[4] = {0.f, 0.f, 0.f, 0.f};
    for (int r = 0; r < 32; r++) {
        int i = w * 32 + r;
        float4 v = *(const float4*)(zb + (size_t)i * N_ + lane * 4);
        float s0 = sigmoidf_(v.x), s1 = sigmoidf_(v.y),
              s2 = sigmoidf_(v.z), s3 = sigmoidf_(v.w);
        f16x2 p0 = { (f16)s0, (f16)s1 }, p1 = { (f16)s2, (f16)s3 };
        *(f16x2*)&T[i * LD + lane * 4]     = p0;   // byte 516*i + 8*lane: 4B-aligned
        *(f16x2*)&T[i * LD + lane * 4 + 2] = p1;
        colacc[0] += s0; colacc[1] += s1; colacc[2] += s2; colacc[3] += s3;
        float rs = s0 + s1 + s2 + s3;
        for (int off = 32; off; off >>= 1) rs += __shfl_down(rs, off, 64);
        if (lane == 0) rbuf[i] = rs;
    }
    #pragma unroll
    for (int k = 0; k < 4; k++) cpart[w][lane * 4 + k] = colacc[k];
    __syncthreads();

    if (tid < 256) {
        float cs = 0.f;
        #pragma unroll
        for (int ww = 0; ww < 8; ww++) cs += cpart[ww][tid];
        Dv[tid] = rsqrtf(1.0f + 1e-6f + 0.5f * (rbuf[tid] + cs));
    }
    __syncthreads();

    // emit: each thread owns column-chunk j8 = (tid&31)*8 across 16 rows.
    const int j8 = (tid & 31) * 8;
    float dj[8];
    #pragma unroll
    for (int k = 0; k < 8; k++) dj[k] = Dv[j8 + k];
    f16* Ob = nA + (size_t)b * (N_ * N_);
    for (int it = 0; it < 16; it++) {
        int i = it * 16 + (tid >> 5);
        float di = Dv[i];
        // direct row read as 4 x f16x2 (4B-aligned; b128 would fault on odd i)
        f16x2 dd[4];
        #pragma unroll
        for (int c = 0; c < 4; c++)
            dd[c] = *(const f16x2*)&T[i * LD + j8 + c * 2];
        f16x8 o;
        #pragma unroll
        for (int k = 0; k < 8; k++) {
            float sij = (float)dd[k >> 1][k & 1];
            float v = 0.5f * (sij + (float)T[(j8 + k) * LD + i]);
            if (i == j8 + k) v += 1.0f;
            o[k] = (f16)(v * di * dj[k]);
        }
        *(f16x8*)&Ob[(size_t)i * N_ + j8] = o;     // global 16B store, aligned
    }
}

// ---------------------------------------------------------------------------
// k_prep: fused weight preprocessing.
// blocks [0,512): XW1t[h,node] = ne[node]·w1[:,h] + b1[h]
// blocks [512,2560): w{2,3}t transpose to f16.
__global__ __launch_bounds__(256) void k_prep(const float* __restrict__ ne,
                                              const float* __restrict__ w1,
                                              const float* __restrict__ b1,
                                              const float* __restrict__ w2,
                                              const float* __restrict__ w3,
                                              f16* __restrict__ XW1t,
                                              f16* __restrict__ w2t,
                                              f16* __restrict__ w3t) {
    int bid = blockIdx.x;
    if (bid < 512) {
        int h = bid, node = threadIdx.x;
        float s = b1[h];
        #pragma unroll 8
        for (int k = 0; k < F_; k++) s += ne[node * F_ + k] * w1[k * H_ + h];
        XW1t[h * N_ + node] = (f16)s;
    } else {
        int idx4 = bid - 512;                    // 0..2047
        int which = idx4 >> 10;                  // 0 -> w2, 1 -> w3
        const float* src = which ? w3 : w2;
        f16* dst = which ? w3t : w2t;
        int idx = (idx4 & 1023) * 256 + threadIdx.x;   // 0..262143
        int k = idx >> 9, n = idx & 511;
        dst[n * H_ + k] = (f16)src[k * H_ + n];
    }
}

// ---------------------------------------------------------------------------
// k_gemm: C(128x128) = A(m,K) @ Bt(n,K)^T. Used only for layer 1 now.
// MODE 0: Out[b][node][512] = relu(acc)
template <int KDIM, int MODE>
__global__ __launch_bounds__(256, 4) void k_gemm(const f16* __restrict__ A, long aBatch,
                                                 const f16* __restrict__ Bt, long bBatch,
                                                 f16* __restrict__ Out,
                                                 const float* __restrict__ bias,
                                                 float* __restrict__ gp) {
    __shared__ f16 As[128 * 64];
    __shared__ f16 Bs[128 * 64];
    const int tid  = threadIdx.x;
    const int lane = tid & 63, wave = tid >> 6;
    const int wm = wave >> 1, wn = wave & 1;

    const int lin = blockIdx.x;
    const int xcd = lin & 7, q = lin >> 3;
    const int n_t = q & 3, p = q >> 2;
    const int grp = xcd * 64 + p;          // 0..511 = (b, m-tile)
    const int b   = grp >> 1, m_t = grp & 1;
    const int m0 = m_t * 128, n0 = n_t * 128;

    const f16* Ab = A + (size_t)b * aBatch;
    const f16* Bb = Bt + (size_t)b * bBatch;

    f32x4 acc[4][4];
    #pragma unroll
    for (int i = 0; i < 4; i++)
        #pragma unroll
        for (int j = 0; j < 4; j++)
            #pragma unroll
            for (int r = 0; r < 4; r++) acc[i][j][r] = 0.0f;

    const int lr = lane >> 3;              // 0..7 row within chunk
    const int kc = (lane & 7) ^ lr;        // global 16B k-chunk to fetch

    const int ln15 = lane & 15;

    for (int kk = 0; kk < KDIM; kk += 64) {
        #pragma unroll
        for (int c = 0; c < 4; c++) {
            int chunk = wave * 4 + c;      // 0..15
            int row = chunk * 8 + lr;      // 0..127
            __builtin_amdgcn_global_load_lds(
                (__attribute__((address_space(1))) void*)(Ab + (size_t)(m0 + row) * KDIM + kk + kc * 8),
                (__attribute__((address_space(3))) void*)(&As[chunk * 512]), 16, 0, 0);
            __builtin_amdgcn_global_load_lds(
                (__attribute__((address_space(1))) void*)(Bb + (size_t)(n0 + row) * KDIM + kk + kc * 8),
                (__attribute__((address_space(3))) void*)(&Bs[chunk * 512]), 16, 0, 0);
        }
        __syncthreads();

        #pragma unroll
        for (int ks = 0; ks < 2; ks++) {
            const int rkc = ks * 4 + (lane >> 4);
            f16x8 aF[4];
            #pragma unroll
            for (int t = 0; t < 4; t++) {
                int ra = wm * 64 + t * 16 + ln15;
                aF[t] = *(const f16x8*)&As[(ra * 8 + (rkc ^ (ra & 7))) * 8];
            }
            #pragma unroll
            for (int h2 = 0; h2 < 2; h2++) {
                f16x8 bF[2];
                #pragma unroll
                for (int t = 0; t < 2; t++) {
                    int rb = wn * 64 + (h2 * 2 + t) * 16 + ln15;
                    bF[t] = *(const f16x8*)&Bs[(rb * 8 + (rkc ^ (rb & 7))) * 8];
                }
                #pragma unroll
                for (int mt = 0; mt < 4; mt++)
                    #pragma unroll
                    for (int t = 0; t < 2; t++)
                        acc[mt][h2 * 2 + t] = __builtin_amdgcn_mfma_f32_16x16x32_f16(aF[mt], bF[t], acc[mt][h2 * 2 + t], 0, 0, 0);
            }
        }
        __syncthreads();
    }

    const int quad = lane >> 4;
    if (MODE == 0) {
        f16* Ob = Out + (size_t)b * (N_ * H_);
        #pragma unroll
        for (int mt = 0; mt < 4; mt++) {
            int node = m0 + wm * 64 + mt * 16 + quad * 4;
            #pragma unroll
            for (int nt = 0; nt < 4; nt++) {
                int h = n0 + wn * 64 + nt * 16 + ln15;
                #pragma unroll
                for (int rr = 0; rr < 4; rr++) {
                    float v = acc[mt][nt][rr];
                    v = v > 0.f ? v : 0.f;
                    Ob[(size_t)(node + rr) * H_ + h] = (f16)v;
                }
            }
        }
    }
}

// ---------------------------------------------------------------------------
// k_fused v4: counted-vmcnt schedule + direct-to-register L2-resident operands.
//   stage 1: U[j,h] = Hin_b @ Wc^T + bias. A (Hin): global_load_lds dbuf
//            (broadcast-shared by waves). B (W): asm global->VGPR dbuf
//            (L2-resident, contiguous fragments) -- no LDS for W at all.
//   stage 2: relu(nA_b @ U). B (U_t) from LDS; A (nA): asm global->VGPR dbuf.
// Per-wave VMEM per step: stage1 = 4 DMA + 8 reg-loads -> BAR_ACQ(12);
// stage2 = 8 reg-loads -> BAR_ACQ(8). LDS reads halved vs v3 (768/block),
// W/nA DMA writes eliminated.
// REDUCE=0: write Hout[b][node][512]. REDUCE=1: node-sum -> gp[b][512].
template <int REDUCE>
__global__ __launch_bounds__(512, 2) void k_fused(const f16* __restrict__ Hin,
                                                  const f16* __restrict__ Wt,
                                                  const float* __restrict__ bias,
                                                  const f16* __restrict__ nA,
                                                  f16* __restrict__ Hout,
                                                  float* __restrict__ gp) {
    __shared__ f16 As[2][16384];   // 2 x (256 rows x 64 f16) = 64 KB (Hin dbuf)
    __shared__ f16 WU[32768];      // U_t [128 h][256 j], chunk-swizzled, 64 KB

    const int tid  = threadIdx.x;
    const int lane = tid & 63, wave = tid >> 6;
    const int ln15 = lane & 15, quad = lane >> 4;
    const int wm = wave >> 1, wn = wave & 1;     // wm: m-quadrant(4), wn: n-half(2)

    // XCD grouping: 4 hc-blocks of one batch land on one XCD (share Hin_b, nA_b in L2)
    const int lin = blockIdx.x;
    const int xcd = lin & 7, p = lin >> 3;
    const int grp = xcd * 128 + p;               // 0..1023
    const int b = grp >> 2, hc = grp & 3;

    const f16* Hb = Hin + (size_t)b * (N_ * H_);
    const f16* Ab = nA + (size_t)b * (N_ * N_);
    const f16* Wc = Wt + (size_t)(hc * 128) * H_;

    const int lr = lane >> 3;
    const int kc = (lane & 7) ^ lr;              // swizzled global 16B k-chunk

    // Hin staging: chunk = 8 rows x 64 f16 = 1 KB; LDS slot s of row r holds
    // global chunk s^(r&7). 4 gload_lds per wave per call.
    auto stageA = [&](int buf, int kt) {
        #pragma unroll
        for (int c = 0; c < 4; c++) {
            int chunk = wave * 4 + c;
            int row = chunk * 8 + lr;            // 0..255
            __builtin_amdgcn_global_load_lds(
                (__attribute__((address_space(1))) void*)(Hb + (size_t)row * H_ + kt * 64 + kc * 8),
                (__attribute__((address_space(3))) void*)(&As[buf][chunk * 512]), 16, 0, 0);
        }
    };

    // per-lane fragment base pointers (contiguous 16B row-slices)
    const f16* wbase[4];
    const f16* abase[4];
    #pragma unroll
    for (int t = 0; t < 4; t++) {
        wbase[t] = Wc + (size_t)(wn * 64 + t * 16 + ln15) * H_ + quad * 8;
        abase[t] = Ab + (size_t)(wm * 64 + t * 16 + ln15) * N_ + quad * 8;
    }

// 8 asm loads: DST[ks*4+t] = fragment (row t, k-octet ks*4+quad) of tile KT
#define LOADW(DST, KT) do { \
    _Pragma("unroll") \
    for (int t_ = 0; t_ < 4; t_++) { \
        const f16* p_ = wbase[t_] + (KT) * 64; \
        GLOADX4(DST[t_], p_, 0); \
        GLOADX4(DST[4 + t_], p_, 64); \
    } } while (0)
#define LOADA2(DST, JT) do { \
    _Pragma("unroll") \
    for (int t_ = 0; t_ < 4; t_++) { \
        const f16* p_ = abase[t_] + (JT) * 64; \
        GLOADX4(DST[t_], p_, 0); \
        GLOADX4(DST[4 + t_], p_, 64); \
    } } while (0)

    f32x4 acc[4][4];
    #pragma unroll
    for (int i = 0; i < 4; i++)
        #pragma unroll
        for (int j = 0; j < 4; j++)
            #pragma unroll
            for (int r = 0; r < 4; r++) acc[i][j][r] = 0.0f;

// stage1 compute: A from LDS (swizzled), B from register set W_
#define S1_STEP(ASBUF, W_) do { \
    __builtin_amdgcn_s_setprio(1); \
    _Pragma("unroll") \
    for (int ks = 0; ks < 2; ks++) { \
        const int rkc = ks * 4 + quad; \
        f16x8 aF[4]; \
        _Pragma("unroll") \
        for (int t_ = 0; t_ < 4; t_++) { \
            int ra = wm * 64 + t_ * 16 + ln15; \
            aF[t_] = *(const f16x8*)&(ASBUF)[(ra * 8 + (rkc ^ (ra & 7))) * 8]; \
        } \
        _Pragma("unroll") \
        for (int mt = 0; mt < 4; mt++) \
            _Pragma("unroll") \
            for (int nt = 0; nt < 4; nt++) \
                acc[mt][nt] = __builtin_amdgcn_mfma_f32_16x16x32_f16(aF[mt], W_[ks * 4 + nt], acc[mt][nt], 0, 0, 0); \
    } \
    __builtin_amdgcn_s_setprio(0); } while (0)

// stage2 compute: A from register set AN_, B (U_t) from LDS (swizzled)
#define S2_STEP(JT, AN_) do { \
    __builtin_amdgcn_s_setprio(1); \
    _Pragma("unroll") \
    for (int ks = 0; ks < 2; ks++) { \
        const int rkc = ks * 4 + quad; \
        f16x8 bF[4]; \
        _Pragma("unroll") \
        for (int t_ = 0; t_ < 4; t_++) { \
            int rb = wn * 64 + t_ * 16 + ln15; \
            int g = (JT) * 8 + rkc; \
            bF[t_] = *(const f16x8*)&WU[rb * 256 + ((g ^ (rb & 7)) * 8)]; \
        } \
        _Pragma("unroll") \
        for (int mt = 0; mt < 4; mt++) \
            _Pragma("unroll") \
            for (int nt = 0; nt < 4; nt++) \
                acc[mt][nt] = __builtin_amdgcn_mfma_f32_16x16x32_f16(AN_[ks * 4 + mt], bF[nt], acc[mt][nt], 0, 0, 0); \
    } \
    __builtin_amdgcn_s_setprio(0); } while (0)

    f16x8 wA[8], wB[8];            // W fragment dbuf (register)
    f16x8 nAa[8], nAb[8];          // nA fragment dbuf (register)

    // ---------------- stage 1: U = Hin @ Wc^T + bias --------------------
    stageA(0, 0); LOADW(wA, 0);                  // 12 in flight
    stageA(1, 1); LOADW(wB, 1); BAR_ACQ(12); S1_STEP(As[0], wA); BAR_REL();  // kt=0
    stageA(0, 2); LOADW(wA, 2); BAR_ACQ(12); S1_STEP(As[1], wB); BAR_REL();  // kt=1
    stageA(1, 3); LOADW(wB, 3); BAR_ACQ(12); S1_STEP(As[0], wA); BAR_REL();  // kt=2
    stageA(0, 4); LOADW(wA, 4); BAR_ACQ(12); S1_STEP(As[1], wB); BAR_REL();  // kt=3
    stageA(1, 5); LOADW(wB, 5); BAR_ACQ(12); S1_STEP(As[0], wA); BAR_REL();  // kt=4
    stageA(0, 6); LOADW(wA, 6); BAR_ACQ(12); S1_STEP(As[1], wB); BAR_REL();  // kt=5
    stageA(1, 7); LOADW(wB, 7); BAR_ACQ(12); S1_STEP(As[0], wA); BAR_REL();  // kt=6
    LOADA2(nAa, 0);             BAR_ACQ(8);  S1_STEP(As[1], wB); BAR_REL();  // kt=7

    // epilogue 1: acc(+bias) -> U_t[h][j] in WU, chunk-swizzled.
    // C layout: m(j) = wm*64+mt*16+quad*4+rr (4 contig j -> f16x4), n(h) = wn*64+nt*16+ln15
    #pragma unroll
    for (int nt = 0; nt < 4; nt++) {
        int hl = wn * 64 + nt * 16 + ln15;
        float bv = bias[hc * 128 + hl];
        #pragma unroll
        for (int mt = 0; mt < 4; mt++) {
            int j = wm * 64 + mt * 16 + quad * 4;
            int slot = (j >> 3) ^ (hl & 7);
            f16x4 v;
            #pragma unroll
            for (int rr = 0; rr < 4; rr++) v[rr] = (f16)(acc[mt][nt][rr] + bv);
            *(f16x4*)&WU[hl * 256 + slot * 8 + (j & 7)] = v;
        }
    }
    // publish U_t: drain own LDS writes, then barrier (nA jt=0 regs stay in flight)
    asm volatile("s_waitcnt lgkmcnt(0)" ::: "memory");
    __builtin_amdgcn_s_barrier();
    __builtin_amdgcn_sched_barrier(0);

    // ---------------- stage 2: relu(nA @ U) -----------------------------
    #pragma unroll
    for (int i = 0; i < 4; i++)
        #pragma unroll
        for (int j = 0; j < 4; j++)
            #pragma unroll
            for (int r = 0; r < 4; r++) acc[i][j][r] = 0.0f;

    LOADA2(nAb, 1); BAR_ACQ(8); S2_STEP(0, nAa); BAR_REL();   // jt=0
    LOADA2(nAa, 2); BAR_ACQ(8); S2_STEP(1, nAb); BAR_REL();   // jt=1
    LOADA2(nAb, 3); BAR_ACQ(8); S2_STEP(2, nAa); BAR_REL();   // jt=2
                    BAR_ACQ(0); S2_STEP(3, nAb); BAR_REL();   // jt=3

    if (REDUCE == 0) {
        f16* Ob = Hout + (size_t)b * (N_ * H_);
        #pragma unroll
        for (int mt = 0; mt < 4; mt++) {
            int node = wm * 64 + mt * 16 + quad * 4;
            #pragma unroll
            for (int nt = 0; nt < 4; nt++) {
                int hg = hc * 128 + wn * 64 + nt * 16 + ln15;
                #pragma unroll
                for (int rr = 0; rr < 4; rr++) {
                    float v = acc[mt][nt][rr];
                    v = v > 0.f ? v : 0.f;
                    Ob[(size_t)(node + rr) * H_ + hg] = (f16)v;
                }
            }
        }
    } else {
        // node-sum readout: this block covers ALL 256 nodes -> gp[b][hc*128 + c]
        float part[4];
        #pragma unroll
        for (int nt = 0; nt < 4; nt++) {
            float s = 0.f;
            #pragma unroll
            for (int mt = 0; mt < 4; mt++)
                #pragma unroll
                for (int rr = 0; rr < 4; rr++) {
                    float v = acc[mt][nt][rr];
                    s += (v > 0.f ? v : 0.f);
                }
            s += __shfl_down(s, 32, 64);
            s += __shfl_down(s, 16, 64);
            part[nt] = s;                        // valid on quad==0 lanes
        }
        __syncthreads();                         // LDS dead; reuse As as float scratch
        float* red = (float*)&As[0][0];          // 8 waves x 64 cols
        if (quad == 0) {
            #pragma unroll
            for (int nt = 0; nt < 4; nt++)
                red[wave * 64 + nt * 16 + ln15] = part[nt];
        }
        __syncthreads();
        if (tid < 128) {
            int wnl = tid >> 6, cl = tid & 63;
            float g = red[(0 * 2 + wnl) * 64 + cl] + red[(1 * 2 + wnl) * 64 + cl]
                    + red[(2 * 2 + wnl) * 64 + cl] + red[(3 * 2 + wnl) * 64 + cl];
            gp[(size_t)b * H_ + hc * 128 + tid] = g;
        }
    }
#undef LOADW
#undef LOADA2
#undef S1_STEP
#undef S2_STEP
}

// ---------------------------------------------------------------------------
// k_logits: logits[b] = (gp[b]/N) @ fcw + fcb.  grid B_ x 256.
__global__ __launch_bounds__(256) void k_logits(const float* __restrict__ gp,
                                                const float* __restrict__ fcw,
                                                const float* __restrict__ fcb,
                                                float* __restrict__ out) {
    int b = blockIdx.x, tid = threadIdx.x;
    const float* g = gp + (size_t)b * H_;
    float g0 = g[tid];
    float g1 = g[tid + 256];
    float p0 = g0 * fcw[tid * 2 + 0] + g1 * fcw[(tid + 256) * 2 + 0];
    float p1 = g0 * fcw[tid * 2 + 1] + g1 * fcw[(tid + 256) * 2 + 1];
    for (int off = 32; off; off >>= 1) {
        p0 += __shfl_down(p0, off, 64);
        p1 += __shfl_down(p1, off, 64);
    }
    __shared__ float r0[4], r1[4];
    int lane = tid & 63, w = tid >> 6;
    if (lane == 0) { r0[w] = p0; r1[w] = p1; }
    __syncthreads();
    const float inv = 1.0f / N_;
    if (tid == 0) out[b * 2 + 0] = (r0[0] + r0[1] + r0[2] + r0[3]) * inv + fcb[0];
    if (tid == 1) out[b * 2 + 1] = (r1[0] + r1[1] + r1[2] + r1[3]) * inv + fcb[1];
}

// ---------------------------------------------------------------------------
extern "C" void kernel_launch(void* const* d_in, const int* in_sizes, int n_in,
                              void* d_out, int out_size, void* d_ws, size_t ws_size,
                              hipStream_t stream) {
    const float* z   = (const float*)d_in[0];
    const float* ne  = (const float*)d_in[1];
    const float* w1  = (const float*)d_in[2];
    const float* b1  = (const float*)d_in[3];
    const float* w2  = (const float*)d_in[4];
    const float* b2  = (const float*)d_in[5];
    const float* w3  = (const float*)d_in[6];
    const float* b3  = (const float*)d_in[7];
    const float* fcw = (const float*)d_in[8];
    const float* fcb = (const float*)d_in[9];
    float* out = (float*)d_out;

    char* ws = (char*)d_ws;
    f16*   T     = (f16*)(ws + 0);            // 67,108,864 (T2/T3 intermediate)
    f16*   nA    = (f16*)(ws + 67108864);     // 33,554,432
    f16*   Hh    = (f16*)(ws + 100663296);    // 67,108,864 (H1)
    float* gpart = (float*)(ws + 100663296);  //    524,288 (alias Hh, H1 dead after F2)
    f16*   XW1t  = (f16*)(ws + 167772160);    //    262,144
    f16*   w2t   = (f16*)(ws + 168034304);    //    524,288
    f16*   w3t   = (f16*)(ws + 168558592);    //    524,288

    // Fused sigmoid/symmetrize/normalize: z -> nA directly (S never hits HBM)
    k_fsum<<<256, 512, 0, stream>>>(z, nA);
    k_prep<<<2560, 256, 0, stream>>>(ne, w1, b1, w2, w3, XW1t, w2t, w3t);

    // Layer 1: H1 = relu(nA @ XW1)
    k_gemm<256, 0><<<2048, 256, 0, stream>>>(nA, 65536, XW1t, 0, Hh, nullptr, nullptr);
    // Layer 2 fused: H2 = relu(nA @ (H1 @ w2 + b2))   (U never touches HBM)
    k_fused<0><<<1024, 512, 0, stream>>>(Hh, w2t, b2, nA, T, nullptr);
    // Layer 3 fused + readout: gp[b][h] = sum_i relu(nA @ (H2 @ w3 + b3))[i][h]
    k_fused<1><<<1024, 512, 0, stream>>>(T, w3t, b3, nA, nullptr, gpart);

    k_logits<<<B_, 256, 0, stream>>>(gpart, fcw, fcb, out);
}

// Round 7
// 298.845 us; speedup vs baseline: 1.4097x; 1.4097x over previous
//
#include <hip/hip_runtime.h>
#include <stdint.h>

#define B_ 256
#define N_ 256
#define F_ 64
#define H_ 512

typedef _Float16 f16;
typedef _Float16 f16x8 __attribute__((ext_vector_type(8)));
typedef _Float16 f16x4 __attribute__((ext_vector_type(4)));
typedef _Float16 f16x2 __attribute__((ext_vector_type(2)));
typedef float    f32x4 __attribute__((ext_vector_type(4)));

__device__ __forceinline__ float sigmoidf_(float x) {
    return 1.0f / (1.0f + __expf(-x));
}

// Counted-vmcnt barrier pair (T3/T4 pattern, round-5 proven):
#define BAR_ACQ(N) do { \
    asm volatile("s_waitcnt vmcnt(" #N ")" ::: "memory"); \
    __builtin_amdgcn_s_barrier(); \
    __builtin_amdgcn_sched_barrier(0); } while (0)
#define BAR_REL() do { \
    __builtin_amdgcn_sched_barrier(0); \
    __builtin_amdgcn_s_barrier(); } while (0)

// ---------------------------------------------------------------------------
// k_fsum v2: fused sigmoid + symmetrize + degree-normalize, one block/batch.
// T[256][256] f16 in LDS with bijective 16B-chunk swizzle:
//   chunk c of row i stored at slot c ^ (i&31) ^ (i>>5).
// All LDS accesses are 16B-aligned b128 (or 8B staging writes); no shuffles,
// no scalar transposed reads (round-5 k_fsum's two structural costs).
// Phases: stage (z->sigmoid->T, col partials in regs) | rowsum (parallel LDS
// pass, 2 thr/row) | Dv | emit (per-thread 8x8 tile pairs, mirror tile
// transposed in registers, coalesced f16x8 global stores).
__global__ __launch_bounds__(512) void k_fsum(const float* __restrict__ z,
                                              f16* __restrict__ nA) {
    __shared__ f16 T[256 * 256];         // 128 KB
    __shared__ float cpart[8][256];      // 8 KB
    __shared__ float rpart[256][2];      // 2 KB
    __shared__ float Dv[256];            // 1 KB   (total ~139 KB, 1 block/CU)

    const int b = blockIdx.x;
    const int tid = threadIdx.x, lane = tid & 63, w = tid >> 6;
    const float* zb = z + (size_t)b * (N_ * N_);

    auto swz = [](int i) { return (i & 31) ^ (i >> 5); };

    // ---- stage: each wave owns 32 rows; lane covers cols [4L, 4L+4) ----
    float colacc[4] = {0.f, 0.f, 0.f, 0.f};
    const int ch = lane >> 1, half = lane & 1;   // 16B chunk, 8B half
    for (int r = 0; r < 32; r++) {
        int i = w * 32 + r;
        float4 v = *(const float4*)(zb + (size_t)i * N_ + lane * 4);
        float s0 = sigmoidf_(v.x), s1 = sigmoidf_(v.y),
              s2 = sigmoidf_(v.z), s3 = sigmoidf_(v.w);
        f16x4 sv = { (f16)s0, (f16)s1, (f16)s2, (f16)s3 };
        *(f16x4*)&T[i * 256 + ((ch ^ swz(i)) << 3) + half * 4] = sv;
        colacc[0] += s0; colacc[1] += s1; colacc[2] += s2; colacc[3] += s3;
    }
    #pragma unroll
    for (int k = 0; k < 4; k++) cpart[w][lane * 4 + k] = colacc[k];
    __syncthreads();

    // ---- rowsum: 2 threads per row, vectorized b128 reads ----
    {
        int i = tid >> 1, h = tid & 1;
        float s = 0.f;
        #pragma unroll
        for (int c = 0; c < 16; c++) {
            int cc = h * 16 + c;
            f16x8 v = *(const f16x8*)&T[i * 256 + ((cc ^ swz(i)) << 3)];
            #pragma unroll
            for (int k = 0; k < 8; k++) s += (float)v[k];
        }
        rpart[i][h] = s;
    }
    __syncthreads();

    if (tid < 256) {
        float cs = 0.f;
        #pragma unroll
        for (int ww = 0; ww < 8; ww++) cs += cpart[ww][tid];
        float rs = rpart[tid][0] + rpart[tid][1];
        Dv[tid] = rsqrtf(1.0f + 1e-6f + 0.5f * (rs + cs));
    }
    __syncthreads();

    // ---- emit: thread -> tiles {tid, 512+tid} of 1024 8x8 tiles ----
    f16* Ob = nA + (size_t)b * (N_ * N_);
    #pragma unroll
    for (int tt = 0; tt < 2; tt++) {
        int tile = tt * 512 + tid;
        int I = tile >> 5, J = tile & 31;        // 32x32 grid of 8x8 tiles
        f16x8 a[8], bm[8];
        #pragma unroll
        for (int r = 0; r < 8; r++) {
            int ia = I * 8 + r;
            a[r] = *(const f16x8*)&T[ia * 256 + ((J ^ swz(ia)) << 3)];
        }
        #pragma unroll
        for (int r = 0; r < 8; r++) {
            int jb = J * 8 + r;
            bm[r] = *(const f16x8*)&T[jb * 256 + ((I ^ swz(jb)) << 3)];
        }
        // a[r][k]  = S[I8+r][J8+k]; bm[k][r] = S[J8+k][I8+r] (reg transpose)
        float dj[8];
        #pragma unroll
        for (int k = 0; k < 8; k++) dj[k] = Dv[J * 8 + k];
        #pragma unroll
        for (int r = 0; r < 8; r++) {
            float di = Dv[I * 8 + r];
            f16x8 o;
            #pragma unroll
            for (int k = 0; k < 8; k++) {
                float v = 0.5f * ((float)a[r][k] + (float)bm[k][r]);
                if (I * 8 + r == J * 8 + k) v += 1.0f;
                o[k] = (f16)(v * di * dj[k]);
            }
            *(f16x8*)&Ob[(size_t)(I * 8 + r) * N_ + J * 8] = o;
        }
    }
}

// ---------------------------------------------------------------------------
// k_prep: fused weight preprocessing.
// blocks [0,512): XW1t[h,node] = ne[node]·w1[:,h] + b1[h]
// blocks [512,2560): w{2,3}t transpose to f16.
__global__ __launch_bounds__(256) void k_prep(const float* __restrict__ ne,
                                              const float* __restrict__ w1,
                                              const float* __restrict__ b1,
                                              const float* __restrict__ w2,
                                              const float* __restrict__ w3,
                                              f16* __restrict__ XW1t,
                                              f16* __restrict__ w2t,
                                              f16* __restrict__ w3t) {
    int bid = blockIdx.x;
    if (bid < 512) {
        int h = bid, node = threadIdx.x;
        float s = b1[h];
        #pragma unroll 8
        for (int k = 0; k < F_; k++) s += ne[node * F_ + k] * w1[k * H_ + h];
        XW1t[h * N_ + node] = (f16)s;
    } else {
        int idx4 = bid - 512;                    // 0..2047
        int which = idx4 >> 10;                  // 0 -> w2, 1 -> w3
        const float* src = which ? w3 : w2;
        f16* dst = which ? w3t : w2t;
        int idx = (idx4 & 1023) * 256 + threadIdx.x;   // 0..262143
        int k = idx >> 9, n = idx & 511;
        dst[n * H_ + k] = (f16)src[k * H_ + n];
    }
}

// ---------------------------------------------------------------------------
// k_gemm: C(128x128) = A(m,K) @ Bt(n,K)^T. Used only for layer 1 now.
// MODE 0: Out[b][node][512] = relu(acc)
template <int KDIM, int MODE>
__global__ __launch_bounds__(256, 4) void k_gemm(const f16* __restrict__ A, long aBatch,
                                                 const f16* __restrict__ Bt, long bBatch,
                                                 f16* __restrict__ Out,
                                                 const float* __restrict__ bias,
                                                 float* __restrict__ gp) {
    __shared__ f16 As[128 * 64];
    __shared__ f16 Bs[128 * 64];
    const int tid  = threadIdx.x;
    const int lane = tid & 63, wave = tid >> 6;
    const int wm = wave >> 1, wn = wave & 1;

    const int lin = blockIdx.x;
    const int xcd = lin & 7, q = lin >> 3;
    const int n_t = q & 3, p = q >> 2;
    const int grp = xcd * 64 + p;          // 0..511 = (b, m-tile)
    const int b   = grp >> 1, m_t = grp & 1;
    const int m0 = m_t * 128, n0 = n_t * 128;

    const f16* Ab = A + (size_t)b * aBatch;
    const f16* Bb = Bt + (size_t)b * bBatch;

    f32x4 acc[4][4];
    #pragma unroll
    for (int i = 0; i < 4; i++)
        #pragma unroll
        for (int j = 0; j < 4; j++)
            #pragma unroll
            for (int r = 0; r < 4; r++) acc[i][j][r] = 0.0f;

    const int lr = lane >> 3;              // 0..7 row within chunk
    const int kc = (lane & 7) ^ lr;        // global 16B k-chunk to fetch

    const int ln15 = lane & 15;

    for (int kk = 0; kk < KDIM; kk += 64) {
        #pragma unroll
        for (int c = 0; c < 4; c++) {
            int chunk = wave * 4 + c;      // 0..15
            int row = chunk * 8 + lr;      // 0..127
            __builtin_amdgcn_global_load_lds(
                (__attribute__((address_space(1))) void*)(Ab + (size_t)(m0 + row) * KDIM + kk + kc * 8),
                (__attribute__((address_space(3))) void*)(&As[chunk * 512]), 16, 0, 0);
            __builtin_amdgcn_global_load_lds(
                (__attribute__((address_space(1))) void*)(Bb + (size_t)(n0 + row) * KDIM + kk + kc * 8),
                (__attribute__((address_space(3))) void*)(&Bs[chunk * 512]), 16, 0, 0);
        }
        __syncthreads();

        #pragma unroll
        for (int ks = 0; ks < 2; ks++) {
            const int rkc = ks * 4 + (lane >> 4);
            f16x8 aF[4];
            #pragma unroll
            for (int t = 0; t < 4; t++) {
                int ra = wm * 64 + t * 16 + ln15;
                aF[t] = *(const f16x8*)&As[(ra * 8 + (rkc ^ (ra & 7))) * 8];
            }
            #pragma unroll
            for (int h2 = 0; h2 < 2; h2++) {
                f16x8 bF[2];
                #pragma unroll
                for (int t = 0; t < 2; t++) {
                    int rb = wn * 64 + (h2 * 2 + t) * 16 + ln15;
                    bF[t] = *(const f16x8*)&Bs[(rb * 8 + (rkc ^ (rb & 7))) * 8];
                }
                #pragma unroll
                for (int mt = 0; mt < 4; mt++)
                    #pragma unroll
                    for (int t = 0; t < 2; t++)
                        acc[mt][h2 * 2 + t] = __builtin_amdgcn_mfma_f32_16x16x32_f16(aF[mt], bF[t], acc[mt][h2 * 2 + t], 0, 0, 0);
            }
        }
        __syncthreads();
    }

    const int quad = lane >> 4;
    if (MODE == 0) {
        f16* Ob = Out + (size_t)b * (N_ * H_);
        #pragma unroll
        for (int mt = 0; mt < 4; mt++) {
            int node = m0 + wm * 64 + mt * 16 + quad * 4;
            #pragma unroll
            for (int nt = 0; nt < 4; nt++) {
                int h = n0 + wn * 64 + nt * 16 + ln15;
                #pragma unroll
                for (int rr = 0; rr < 4; rr++) {
                    float v = acc[mt][nt][rr];
                    v = v > 0.f ? v : 0.f;
                    Ob[(size_t)(node + rr) * H_ + h] = (f16)v;
                }
            }
        }
    }
}

// ---------------------------------------------------------------------------
// k_fused (round-5 proven version, 78.6us): counted-vmcnt schedule.
//   stage 1: U[j,h] = Hin_b @ Wc^T + bias (256x128, K=512), A+B staged via
//            global_load_lds dbuf; U_t kept in LDS (XOR-chunk swizzled).
//   stage 2: relu(nA_b @ U) (256x128, K=256), B from LDS, A staged dbuf.
// Barriers never drain vmcnt to 0 in the main loops (BAR_ACQ(6|4)).
// REDUCE=0: write Hout[b][node][512]. REDUCE=1: node-sum -> gp[b][512].
template <int REDUCE>
__global__ __launch_bounds__(512, 2) void k_fused(const f16* __restrict__ Hin,
                                                  const f16* __restrict__ Wt,
                                                  const float* __restrict__ bias,
                                                  const f16* __restrict__ nA,
                                                  f16* __restrict__ Hout,
                                                  float* __restrict__ gp) {
    __shared__ f16 As[2][16384];   // 2 x (256 rows x 64 f16) = 64 KB
    __shared__ f16 WU[32768];      // stage1: Ws[2][8192] (2x16KB); stage2: U_t 128x256

    const int tid  = threadIdx.x;
    const int lane = tid & 63, wave = tid >> 6;
    const int ln15 = lane & 15, quad = lane >> 4;
    const int wm = wave >> 1, wn = wave & 1;     // wm: m-quadrant(4), wn: n-half(2)

    // XCD grouping: 4 hc-blocks of one batch land on one XCD (share Hin_b, nA_b in L2)
    const int lin = blockIdx.x;
    const int xcd = lin & 7, p = lin >> 3;
    const int grp = xcd * 128 + p;               // 0..1023
    const int b = grp >> 2, hc = grp & 3;

    const f16* Hb = Hin + (size_t)b * (N_ * H_);
    const f16* Ab = nA + (size_t)b * (N_ * N_);
    const f16* Wc = Wt + (size_t)(hc * 128) * H_;

    const int lr = lane >> 3;
    const int kc = (lane & 7) ^ lr;              // swizzled global 16B k-chunk

    // loaders: chunk = 8 rows x 64 f16 = 1 KB; LDS slot s of row r holds global chunk s^(r&7)
    auto stage1 = [&](int buf, int kt) {         // 6 gload_lds per wave
        #pragma unroll
        for (int c = 0; c < 4; c++) {            // Hin: 32 chunks / 8 waves
            int chunk = wave * 4 + c;
            int row = chunk * 8 + lr;            // 0..255
            __builtin_amdgcn_global_load_lds(
                (__attribute__((address_space(1))) void*)(Hb + (size_t)row * H_ + kt * 64 + kc * 8),
                (__attribute__((address_space(3))) void*)(&As[buf][chunk * 512]), 16, 0, 0);
        }
        #pragma unroll
        for (int c = 0; c < 2; c++) {            // Wt: 16 chunks / 8 waves
            int chunk = wave * 2 + c;
            int row = chunk * 8 + lr;            // 0..127
            __builtin_amdgcn_global_load_lds(
                (__attribute__((address_space(1))) void*)(Wc + (size_t)row * H_ + kt * 64 + kc * 8),
                (__attribute__((address_space(3))) void*)(&WU[buf * 8192 + chunk * 512]), 16, 0, 0);
        }
    };
    auto stage2 = [&](int buf, int jt) {         // 4 gload_lds per wave
        #pragma unroll
        for (int c = 0; c < 4; c++) {            // nA: 32 chunks / 8 waves
            int chunk = wave * 4 + c;
            int row = chunk * 8 + lr;
            __builtin_amdgcn_global_load_lds(
                (__attribute__((address_space(1))) void*)(Ab + (size_t)row * N_ + jt * 64 + kc * 8),
                (__attribute__((address_space(3))) void*)(&As[buf][chunk * 512]), 16, 0, 0);
        }
    };

    f32x4 acc[4][4];
    #pragma unroll
    for (int i = 0; i < 4; i++)
        #pragma unroll
        for (int j = 0; j < 4; j++)
            #pragma unroll
            for (int r = 0; r < 4; r++) acc[i][j][r] = 0.0f;

    // ---------------- stage 1: U = Hin @ Wc^T + bias --------------------
    stage1(0, 0);                                // 6 loads in flight; no drain
    for (int kt = 0; kt < 8; ++kt) {
        const int buf = kt & 1;
        if (kt < 7) {
            stage1(buf ^ 1, kt + 1);             // +6 (12 in flight)
            BAR_ACQ(6);                          // oldest 6 (tile kt) landed
        } else {
            stage2(0, 0);                        // +4: prefetch first nA tile
            BAR_ACQ(4);                          // oldest 6 (tile 7) landed
        }
        __builtin_amdgcn_s_setprio(1);
        #pragma unroll
        for (int ks = 0; ks < 2; ks++) {
            const int rkc = ks * 4 + quad;
            f16x8 aF[4], bF[4];
            #pragma unroll
            for (int t = 0; t < 4; t++) {
                int ra = wm * 64 + t * 16 + ln15;          // Hin row (j)
                aF[t] = *(const f16x8*)&As[buf][(ra * 8 + (rkc ^ (ra & 7))) * 8];
            }
            #pragma unroll
            for (int t = 0; t < 4; t++) {
                int rb = wn * 64 + t * 16 + ln15;          // Wt row (h), 0..127
                bF[t] = *(const f16x8*)&WU[buf * 8192 + (rb * 8 + (rkc ^ (rb & 7))) * 8];
            }
            #pragma unroll
            for (int mt = 0; mt < 4; mt++)
                #pragma unroll
                for (int nt = 0; nt < 4; nt++)
                    acc[mt][nt] = __builtin_amdgcn_mfma_f32_16x16x32_f16(aF[mt], bF[nt], acc[mt][nt], 0, 0, 0);
        }
        __builtin_amdgcn_s_setprio(0);
        BAR_REL();                               // no drain: prefetch stays in flight
    }

    // epilogue 1: acc(+bias) -> U_t[h][j] in WU, chunk-swizzled.
    // C layout: m(j) = wm*64+mt*16+quad*4+rr (4 consecutive j -> f16x4), n(h) = wn*64+nt*16+ln15
    #pragma unroll
    for (int nt = 0; nt < 4; nt++) {
        int hl = wn * 64 + nt * 16 + ln15;
        float bv = bias[hc * 128 + hl];
        #pragma unroll
        for (int mt = 0; mt < 4; mt++) {
            int j = wm * 64 + mt * 16 + quad * 4;
            int slot = (j >> 3) ^ (hl & 7);
            f16x4 v;
            #pragma unroll
            for (int rr = 0; rr < 4; rr++) v[rr] = (f16)(acc[mt][nt][rr] + bv);
            *(f16x4*)&WU[hl * 256 + slot * 8 + (j & 7)] = v;
        }
    }
    // publish U_t: drain own LDS writes, then barrier (vmcnt stays 4: jt=0 prefetch)
    asm volatile("s_waitcnt lgkmcnt(0)" ::: "memory");
    __builtin_amdgcn_s_barrier();
    __builtin_amdgcn_sched_barrier(0);

    // ---------------- stage 2: relu(nA @ U) -----------------------------
    #pragma unroll
    for (int i = 0; i < 4; i++)
        #pragma unroll
        for (int j = 0; j < 4; j++)
            #pragma unroll
            for (int r = 0; r < 4; r++) acc[i][j][r] = 0.0f;

    for (int jt = 0; jt < 4; ++jt) {
        const int buf = jt & 1;
        if (jt < 3) {
            stage2(buf ^ 1, jt + 1);             // +4 (8 in flight)
            BAR_ACQ(4);                          // oldest 4 (tile jt) landed
        } else {
            BAR_ACQ(0);                          // last tile: drain remaining
        }
        __builtin_amdgcn_s_setprio(1);
        #pragma unroll
        for (int ks = 0; ks < 2; ks++) {
            const int rkc = ks * 4 + quad;
            f16x8 aF[4], bF[4];
            #pragma unroll
            for (int t = 0; t < 4; t++) {
                int ra = wm * 64 + t * 16 + ln15;          // nA row (i)
                aF[t] = *(const f16x8*)&As[buf][(ra * 8 + (rkc ^ (ra & 7))) * 8];
            }
            #pragma unroll
            for (int t = 0; t < 4; t++) {
                int rb = wn * 64 + t * 16 + ln15;          // U_t row (h), 0..127
                int g = jt * 8 + rkc;                      // global 8-f16 chunk in row
                bF[t] = *(const f16x8*)&WU[rb * 256 + ((g ^ (rb & 7)) * 8)];
            }
            #pragma unroll
            for (int mt = 0; mt < 4; mt++)
                #pragma unroll
                for (int nt = 0; nt < 4; nt++)
                    acc[mt][nt] = __builtin_amdgcn_mfma_f32_16x16x32_f16(aF[mt], bF[nt], acc[mt][nt], 0, 0, 0);
        }
        __builtin_amdgcn_s_setprio(0);
        BAR_REL();
    }

    if (REDUCE == 0) {
        f16* Ob = Hout + (size_t)b * (N_ * H_);
        #pragma unroll
        for (int mt = 0; mt < 4; mt++) {
            int node = wm * 64 + mt * 16 + quad * 4;
            #pragma unroll
            for (int nt = 0; nt < 4; nt++) {
                int hg = hc * 128 + wn * 64 + nt * 16 + ln15;
                #pragma unroll
                for (int rr = 0; rr < 4; rr++) {
                    float v = acc[mt][nt][rr];
                    v = v > 0.f ? v : 0.f;
                    Ob[(size_t)(node + rr) * H_ + hg] = (f16)v;
                }
            }
        }
    } else {
        // node-sum readout: this block covers ALL 256 nodes -> gp[b][hc*128 + c]
        float part[4];
        #pragma unroll
        for (int nt = 0; nt < 4; nt++) {
            float s = 0.f;
            #pragma unroll
            for (int mt = 0; mt < 4; mt++)
                #pragma unroll
                for (int rr = 0; rr < 4; rr++) {
                    float v = acc[mt][nt][rr];
                    s += (v > 0.f ? v : 0.f);
                }
            s += __shfl_down(s, 32, 64);
            s += __shfl_down(s, 16, 64);
            part[nt] = s;                        // valid on quad==0 lanes
        }
        __syncthreads();                         // LDS dead; reuse As as float scratch
        float* red = (float*)&As[0][0];          // 8 waves x 64 cols
        if (quad == 0) {
            #pragma unroll
            for (int nt = 0; nt < 4; nt++)
                red[wave * 64 + nt * 16 + ln15] = part[nt];
        }
        __syncthreads();
        if (tid < 128) {
            int wnl = tid >> 6, cl = tid & 63;
            float g = red[(0 * 2 + wnl) * 64 + cl] + red[(1 * 2 + wnl) * 64 + cl]
                    + red[(2 * 2 + wnl) * 64 + cl] + red[(3 * 2 + wnl) * 64 + cl];
            gp[(size_t)b * H_ + hc * 128 + tid] = g;
        }
    }
}

// ---------------------------------------------------------------------------
// k_logits: logits[b] = (gp[b]/N) @ fcw + fcb.  grid B_ x 256.
__global__ __launch_bounds__(256) void k_logits(const float* __restrict__ gp,
                                                const float* __restrict__ fcw,
                                                const float* __restrict__ fcb,
                                                float* __restrict__ out) {
    int b = blockIdx.x, tid = threadIdx.x;
    const float* g = gp + (size_t)b * H_;
    float g0 = g[tid];
    float g1 = g[tid + 256];
    float p0 = g0 * fcw[tid * 2 + 0] + g1 * fcw[(tid + 256) * 2 + 0];
    float p1 = g0 * fcw[tid * 2 + 1] + g1 * fcw[(tid + 256) * 2 + 1];
    for (int off = 32; off; off >>= 1) {
        p0 += __shfl_down(p0, off, 64);
        p1 += __shfl_down(p1, off, 64);
    }
    __shared__ float r0[4], r1[4];
    int lane = tid & 63, w = tid >> 6;
    if (lane == 0) { r0[w] = p0; r1[w] = p1; }
    __syncthreads();
    const float inv = 1.0f / N_;
    if (tid == 0) out[b * 2 + 0] = (r0[0] + r0[1] + r0[2] + r0[3]) * inv + fcb[0];
    if (tid == 1) out[b * 2 + 1] = (r1[0] + r1[1] + r1[2] + r1[3]) * inv + fcb[1];
}

// ---------------------------------------------------------------------------
extern "C" void kernel_launch(void* const* d_in, const int* in_sizes, int n_in,
                              void* d_out, int out_size, void* d_ws, size_t ws_size,
                              hipStream_t stream) {
    const float* z   = (const float*)d_in[0];
    const float* ne  = (const float*)d_in[1];
    const float* w1  = (const float*)d_in[2];
    const float* b1  = (const float*)d_in[3];
    const float* w2  = (const float*)d_in[4];
    const float* b2  = (const float*)d_in[5];
    const float* w3  = (const float*)d_in[6];
    const float* b3  = (const float*)d_in[7];
    const float* fcw = (const float*)d_in[8];
    const float* fcb = (const float*)d_in[9];
    float* out = (float*)d_out;

    char* ws = (char*)d_ws;
    f16*   T     = (f16*)(ws + 0);            // 67,108,864 (T2/T3 intermediate)
    f16*   nA    = (f16*)(ws + 67108864);     // 33,554,432
    f16*   Hh    = (f16*)(ws + 100663296);    // 67,108,864 (H1)
    float* gpart = (float*)(ws + 100663296);  //    524,288 (alias Hh, H1 dead after F2)
    f16*   XW1t  = (f16*)(ws + 167772160);    //    262,144
    f16*   w2t   = (f16*)(ws + 168034304);    //    524,288
    f16*   w3t   = (f16*)(ws + 168558592);    //    524,288

    // Fused sigmoid/symmetrize/normalize: z -> nA directly (S never hits HBM)
    k_fsum<<<256, 512, 0, stream>>>(z, nA);
    k_prep<<<2560, 256, 0, stream>>>(ne, w1, b1, w2, w3, XW1t, w2t, w3t);

    // Layer 1: H1 = relu(nA @ XW1)
    k_gemm<256, 0><<<2048, 256, 0, stream>>>(nA, 65536, XW1t, 0, Hh, nullptr, nullptr);
    // Layer 2 fused: H2 = relu(nA @ (H1 @ w2 + b2))   (U never touches HBM)
    k_fused<0><<<1024, 512, 0, stream>>>(Hh, w2t, b2, nA, T, nullptr);
    // Layer 3 fused + readout: gp[b][h] = sum_i relu(nA @ (H2 @ w3 + b3))[i][h]
    k_fused<1><<<1024, 512, 0, stream>>>(T, w3t, b3, nA, nullptr, gpart);

    k_logits<<<B_, 256, 0, stream>>>(gpart, fcw, fcb, out);
}

// Round 8
// 293.225 us; speedup vs baseline: 1.4367x; 1.0192x over previous
//
#include <hip/hip_runtime.h>
#include <stdint.h>

#define B_ 256
#define N_ 256
#define F_ 64
#define H_ 512

typedef _Float16 f16;
typedef _Float16 f16x8 __attribute__((ext_vector_type(8)));
typedef _Float16 f16x4 __attribute__((ext_vector_type(4)));
typedef _Float16 f16x2 __attribute__((ext_vector_type(2)));
typedef float    f32x4 __attribute__((ext_vector_type(4)));

__device__ __forceinline__ float sigmoidf_(float x) {
    return 1.0f / (1.0f + __expf(-x));
}

// Counted-vmcnt barrier pair (T3/T4 pattern, round-5 proven):
#define BAR_ACQ(N) do { \
    asm volatile("s_waitcnt vmcnt(" #N ")" ::: "memory"); \
    __builtin_amdgcn_s_barrier(); \
    __builtin_amdgcn_sched_barrier(0); } while (0)
#define BAR_REL() do { \
    __builtin_amdgcn_sched_barrier(0); \
    __builtin_amdgcn_s_barrier(); } while (0)

// ---------------------------------------------------------------------------
// k_fsum v2 (round-7 proven): fused sigmoid + symmetrize + degree-normalize,
// one block/batch, bijective 16B-chunk swizzled T, all-b128 LDS accesses.
__global__ __launch_bounds__(512) void k_fsum(const float* __restrict__ z,
                                              f16* __restrict__ nA) {
    __shared__ f16 T[256 * 256];         // 128 KB
    __shared__ float cpart[8][256];      // 8 KB
    __shared__ float rpart[256][2];      // 2 KB
    __shared__ float Dv[256];            // 1 KB

    const int b = blockIdx.x;
    const int tid = threadIdx.x, lane = tid & 63, w = tid >> 6;
    const float* zb = z + (size_t)b * (N_ * N_);

    auto swz = [](int i) { return (i & 31) ^ (i >> 5); };

    float colacc[4] = {0.f, 0.f, 0.f, 0.f};
    const int ch = lane >> 1, half = lane & 1;
    for (int r = 0; r < 32; r++) {
        int i = w * 32 + r;
        float4 v = *(const float4*)(zb + (size_t)i * N_ + lane * 4);
        float s0 = sigmoidf_(v.x), s1 = sigmoidf_(v.y),
              s2 = sigmoidf_(v.z), s3 = sigmoidf_(v.w);
        f16x4 sv = { (f16)s0, (f16)s1, (f16)s2, (f16)s3 };
        *(f16x4*)&T[i * 256 + ((ch ^ swz(i)) << 3) + half * 4] = sv;
        colacc[0] += s0; colacc[1] += s1; colacc[2] += s2; colacc[3] += s3;
    }
    #pragma unroll
    for (int k = 0; k < 4; k++) cpart[w][lane * 4 + k] = colacc[k];
    __syncthreads();

    {
        int i = tid >> 1, h = tid & 1;
        float s = 0.f;
        #pragma unroll
        for (int c = 0; c < 16; c++) {
            int cc = h * 16 + c;
            f16x8 v = *(const f16x8*)&T[i * 256 + ((cc ^ swz(i)) << 3)];
            #pragma unroll
            for (int k = 0; k < 8; k++) s += (float)v[k];
        }
        rpart[i][h] = s;
    }
    __syncthreads();

    if (tid < 256) {
        float cs = 0.f;
        #pragma unroll
        for (int ww = 0; ww < 8; ww++) cs += cpart[ww][tid];
        float rs = rpart[tid][0] + rpart[tid][1];
        Dv[tid] = rsqrtf(1.0f + 1e-6f + 0.5f * (rs + cs));
    }
    __syncthreads();

    f16* Ob = nA + (size_t)b * (N_ * N_);
    #pragma unroll
    for (int tt = 0; tt < 2; tt++) {
        int tile = tt * 512 + tid;
        int I = tile >> 5, J = tile & 31;
        f16x8 a[8], bm[8];
        #pragma unroll
        for (int r = 0; r < 8; r++) {
            int ia = I * 8 + r;
            a[r] = *(const f16x8*)&T[ia * 256 + ((J ^ swz(ia)) << 3)];
        }
        #pragma unroll
        for (int r = 0; r < 8; r++) {
            int jb = J * 8 + r;
            bm[r] = *(const f16x8*)&T[jb * 256 + ((I ^ swz(jb)) << 3)];
        }
        float dj[8];
        #pragma unroll
        for (int k = 0; k < 8; k++) dj[k] = Dv[J * 8 + k];
        #pragma unroll
        for (int r = 0; r < 8; r++) {
            float di = Dv[I * 8 + r];
            f16x8 o;
            #pragma unroll
            for (int k = 0; k < 8; k++) {
                float v = 0.5f * ((float)a[r][k] + (float)bm[k][r]);
                if (I * 8 + r == J * 8 + k) v += 1.0f;
                o[k] = (f16)(v * di * dj[k]);
            }
            *(f16x8*)&Ob[(size_t)(I * 8 + r) * N_ + J * 8] = o;
        }
    }
}

// ---------------------------------------------------------------------------
// k_prep: fused weight preprocessing.
__global__ __launch_bounds__(256) void k_prep(const float* __restrict__ ne,
                                              const float* __restrict__ w1,
                                              const float* __restrict__ b1,
                                              const float* __restrict__ w2,
                                              const float* __restrict__ w3,
                                              f16* __restrict__ XW1t,
                                              f16* __restrict__ w2t,
                                              f16* __restrict__ w3t) {
    int bid = blockIdx.x;
    if (bid < 512) {
        int h = bid, node = threadIdx.x;
        float s = b1[h];
        #pragma unroll 8
        for (int k = 0; k < F_; k++) s += ne[node * F_ + k] * w1[k * H_ + h];
        XW1t[h * N_ + node] = (f16)s;
    } else {
        int idx4 = bid - 512;
        int which = idx4 >> 10;
        const float* src = which ? w3 : w2;
        f16* dst = which ? w3t : w2t;
        int idx = (idx4 & 1023) * 256 + threadIdx.x;
        int k = idx >> 9, n = idx & 511;
        dst[n * H_ + k] = (f16)src[k * H_ + n];
    }
}

// ---------------------------------------------------------------------------
// k_gemm: C(128x128) = A(m,K) @ Bt(n,K)^T. Layer 1 only (4 blocks/CU).
template <int KDIM, int MODE>
__global__ __launch_bounds__(256, 4) void k_gemm(const f16* __restrict__ A, long aBatch,
                                                 const f16* __restrict__ Bt, long bBatch,
                                                 f16* __restrict__ Out,
                                                 const float* __restrict__ bias,
                                                 float* __restrict__ gp) {
    __shared__ f16 As[128 * 64];
    __shared__ f16 Bs[128 * 64];
    const int tid  = threadIdx.x;
    const int lane = tid & 63, wave = tid >> 6;
    const int wm = wave >> 1, wn = wave & 1;

    const int lin = blockIdx.x;
    const int xcd = lin & 7, q = lin >> 3;
    const int n_t = q & 3, p = q >> 2;
    const int grp = xcd * 64 + p;
    const int b   = grp >> 1, m_t = grp & 1;
    const int m0 = m_t * 128, n0 = n_t * 128;

    const f16* Ab = A + (size_t)b * aBatch;
    const f16* Bb = Bt + (size_t)b * bBatch;

    f32x4 acc[4][4];
    #pragma unroll
    for (int i = 0; i < 4; i++)
        #pragma unroll
        for (int j = 0; j < 4; j++)
            #pragma unroll
            for (int r = 0; r < 4; r++) acc[i][j][r] = 0.0f;

    const int lr = lane >> 3;
    const int kc = (lane & 7) ^ lr;
    const int ln15 = lane & 15;

    for (int kk = 0; kk < KDIM; kk += 64) {
        #pragma unroll
        for (int c = 0; c < 4; c++) {
            int chunk = wave * 4 + c;
            int row = chunk * 8 + lr;
            __builtin_amdgcn_global_load_lds(
                (__attribute__((address_space(1))) void*)(Ab + (size_t)(m0 + row) * KDIM + kk + kc * 8),
                (__attribute__((address_space(3))) void*)(&As[chunk * 512]), 16, 0, 0);
            __builtin_amdgcn_global_load_lds(
                (__attribute__((address_space(1))) void*)(Bb + (size_t)(n0 + row) * KDIM + kk + kc * 8),
                (__attribute__((address_space(3))) void*)(&Bs[chunk * 512]), 16, 0, 0);
        }
        __syncthreads();

        #pragma unroll
        for (int ks = 0; ks < 2; ks++) {
            const int rkc = ks * 4 + (lane >> 4);
            f16x8 aF[4];
            #pragma unroll
            for (int t = 0; t < 4; t++) {
                int ra = wm * 64 + t * 16 + ln15;
                aF[t] = *(const f16x8*)&As[(ra * 8 + (rkc ^ (ra & 7))) * 8];
            }
            #pragma unroll
            for (int h2 = 0; h2 < 2; h2++) {
                f16x8 bF[2];
                #pragma unroll
                for (int t = 0; t < 2; t++) {
                    int rb = wn * 64 + (h2 * 2 + t) * 16 + ln15;
                    bF[t] = *(const f16x8*)&Bs[(rb * 8 + (rkc ^ (rb & 7))) * 8];
                }
                #pragma unroll
                for (int mt = 0; mt < 4; mt++)
                    #pragma unroll
                    for (int t = 0; t < 2; t++)
                        acc[mt][h2 * 2 + t] = __builtin_amdgcn_mfma_f32_16x16x32_f16(aF[mt], bF[t], acc[mt][h2 * 2 + t], 0, 0, 0);
            }
        }
        __syncthreads();
    }

    const int quad = lane >> 4;
    if (MODE == 0) {
        f16* Ob = Out + (size_t)b * (N_ * H_);
        #pragma unroll
        for (int mt = 0; mt < 4; mt++) {
            int node = m0 + wm * 64 + mt * 16 + quad * 4;
            #pragma unroll
            for (int nt = 0; nt < 4; nt++) {
                int h = n0 + wn * 64 + nt * 16 + ln15;
                #pragma unroll
                for (int rr = 0; rr < 4; rr++) {
                    float v = acc[mt][nt][rr];
                    v = v > 0.f ? v : 0.f;
                    Ob[(size_t)(node + rr) * H_ + h] = (f16)v;
                }
            }
        }
    }
}

// ---------------------------------------------------------------------------
// k_fused v5: round-5 dataflow + counted-vmcnt schedule, 16 waves (1024 thr).
// Wave tile 64x32 (wm=wave>>2 over 256 rows, wn=wave&3 over 128 cols).
// 4 waves/SIMD (vs 2) -> latency hiding doubles; LDS reads +50% (reuse drop)
// but LDS was only ~35% busy. vmcnt recounted: stage1 = 3 gload_lds/wave
// (2 Hin + 1 W chunk), stage2 = 2 (nA chunks).
// REDUCE=0: write Hout[b][node][512]. REDUCE=1: node-sum -> gp[b][512].
template <int REDUCE>
__global__ __launch_bounds__(1024, 4) void k_fused(const f16* __restrict__ Hin,
                                                   const f16* __restrict__ Wt,
                                                   const float* __restrict__ bias,
                                                   const f16* __restrict__ nA,
                                                   f16* __restrict__ Hout,
                                                   float* __restrict__ gp) {
    __shared__ f16 As[2][16384];   // 2 x (256 rows x 64 f16) = 64 KB
    __shared__ f16 WU[32768];      // stage1: Ws[2][8192]; stage2: U_t 128x256

    const int tid  = threadIdx.x;
    const int lane = tid & 63, wave = tid >> 6;      // wave 0..15
    const int ln15 = lane & 15, quad = lane >> 4;
    const int wm = wave >> 2, wn = wave & 3;         // wm: 4 m-quadrants, wn: 4 n-slices(32)

    const int lin = blockIdx.x;
    const int xcd = lin & 7, p = lin >> 3;
    const int grp = xcd * 128 + p;                   // 0..1023
    const int b = grp >> 2, hc = grp & 3;

    const f16* Hb = Hin + (size_t)b * (N_ * H_);
    const f16* Ab = nA + (size_t)b * (N_ * N_);
    const f16* Wc = Wt + (size_t)(hc * 128) * H_;

    const int lr = lane >> 3;
    const int kc = (lane & 7) ^ lr;                  // swizzled global 16B k-chunk

    // loaders: chunk = 8 rows x 64 f16 = 1 KB; LDS slot s of row r holds chunk s^(r&7)
    auto stage1 = [&](int buf, int kt) {             // 3 gload_lds per wave
        #pragma unroll
        for (int c = 0; c < 2; c++) {                // Hin: 32 chunks / 16 waves
            int chunk = wave * 2 + c;
            int row = chunk * 8 + lr;                // 0..255
            __builtin_amdgcn_global_load_lds(
                (__attribute__((address_space(1))) void*)(Hb + (size_t)row * H_ + kt * 64 + kc * 8),
                (__attribute__((address_space(3))) void*)(&As[buf][chunk * 512]), 16, 0, 0);
        }
        {                                            // Wt: 16 chunks / 16 waves
            int chunk = wave;
            int row = chunk * 8 + lr;                // 0..127
            __builtin_amdgcn_global_load_lds(
                (__attribute__((address_space(1))) void*)(Wc + (size_t)row * H_ + kt * 64 + kc * 8),
                (__attribute__((address_space(3))) void*)(&WU[buf * 8192 + chunk * 512]), 16, 0, 0);
        }
    };
    auto stage2 = [&](int buf, int jt) {             // 2 gload_lds per wave
        #pragma unroll
        for (int c = 0; c < 2; c++) {                // nA: 32 chunks / 16 waves
            int chunk = wave * 2 + c;
            int row = chunk * 8 + lr;
            __builtin_amdgcn_global_load_lds(
                (__attribute__((address_space(1))) void*)(Ab + (size_t)row * N_ + jt * 64 + kc * 8),
                (__attribute__((address_space(3))) void*)(&As[buf][chunk * 512]), 16, 0, 0);
        }
    };

    f32x4 acc[4][2];
    #pragma unroll
    for (int i = 0; i < 4; i++)
        #pragma unroll
        for (int j = 0; j < 2; j++)
            #pragma unroll
            for (int r = 0; r < 4; r++) acc[i][j][r] = 0.0f;

    // ---------------- stage 1: U = Hin @ Wc^T + bias --------------------
    stage1(0, 0);                                    // 3 in flight
    for (int kt = 0; kt < 8; ++kt) {
        const int buf = kt & 1;
        if (kt < 7) {
            stage1(buf ^ 1, kt + 1);                 // +3 (6 in flight)
            BAR_ACQ(3);                              // oldest 3 (tile kt) landed
        } else {
            stage2(0, 0);                            // +2: prefetch first nA tile
            BAR_ACQ(2);                              // tile 7's 3 landed
        }
        __builtin_amdgcn_s_setprio(1);
        #pragma unroll
        for (int ks = 0; ks < 2; ks++) {
            const int rkc = ks * 4 + quad;
            f16x8 aF[4], bF[2];
            #pragma unroll
            for (int t = 0; t < 4; t++) {
                int ra = wm * 64 + t * 16 + ln15;            // Hin row (j)
                aF[t] = *(const f16x8*)&As[buf][(ra * 8 + (rkc ^ (ra & 7))) * 8];
            }
            #pragma unroll
            for (int t = 0; t < 2; t++) {
                int rb = wn * 32 + t * 16 + ln15;            // Wt row (h), 0..127
                bF[t] = *(const f16x8*)&WU[buf * 8192 + (rb * 8 + (rkc ^ (rb & 7))) * 8];
            }
            #pragma unroll
            for (int mt = 0; mt < 4; mt++)
                #pragma unroll
                for (int nt = 0; nt < 2; nt++)
                    acc[mt][nt] = __builtin_amdgcn_mfma_f32_16x16x32_f16(aF[mt], bF[nt], acc[mt][nt], 0, 0, 0);
        }
        __builtin_amdgcn_s_setprio(0);
        BAR_REL();                                   // no drain: prefetch stays in flight
    }

    // epilogue 1: acc(+bias) -> U_t[h][j] in WU, chunk-swizzled.
    #pragma unroll
    for (int nt = 0; nt < 2; nt++) {
        int hl = wn * 32 + nt * 16 + ln15;
        float bv = bias[hc * 128 + hl];
        #pragma unroll
        for (int mt = 0; mt < 4; mt++) {
            int j = wm * 64 + mt * 16 + quad * 4;
            int slot = (j >> 3) ^ (hl & 7);
            f16x4 v;
            #pragma unroll
            for (int rr = 0; rr < 4; rr++) v[rr] = (f16)(acc[mt][nt][rr] + bv);
            *(f16x4*)&WU[hl * 256 + slot * 8 + (j & 7)] = v;
        }
    }
    // publish U_t: drain own LDS writes, then barrier (vmcnt stays 2: jt=0 prefetch)
    asm volatile("s_waitcnt lgkmcnt(0)" ::: "memory");
    __builtin_amdgcn_s_barrier();
    __builtin_amdgcn_sched_barrier(0);

    // ---------------- stage 2: relu(nA @ U) -----------------------------
    #pragma unroll
    for (int i = 0; i < 4; i++)
        #pragma unroll
        for (int j = 0; j < 2; j++)
            #pragma unroll
            for (int r = 0; r < 4; r++) acc[i][j][r] = 0.0f;

    for (int jt = 0; jt < 4; ++jt) {
        const int buf = jt & 1;
        if (jt < 3) {
            stage2(buf ^ 1, jt + 1);                 // +2 (4 in flight)
            BAR_ACQ(2);                              // oldest 2 (tile jt) landed
        } else {
            BAR_ACQ(0);                              // last tile: drain remaining
        }
        __builtin_amdgcn_s_setprio(1);
        #pragma unroll
        for (int ks = 0; ks < 2; ks++) {
            const int rkc = ks * 4 + quad;
            f16x8 aF[4], bF[2];
            #pragma unroll
            for (int t = 0; t < 4; t++) {
                int ra = wm * 64 + t * 16 + ln15;            // nA row (i)
                aF[t] = *(const f16x8*)&As[buf][(ra * 8 + (rkc ^ (ra & 7))) * 8];
            }
            #pragma unroll
            for (int t = 0; t < 2; t++) {
                int rb = wn * 32 + t * 16 + ln15;            // U_t row (h), 0..127
                int g = jt * 8 + rkc;                        // global 8-f16 chunk in row
                bF[t] = *(const f16x8*)&WU[rb * 256 + ((g ^ (rb & 7)) * 8)];
            }
            #pragma unroll
            for (int mt = 0; mt < 4; mt++)
                #pragma unroll
                for (int nt = 0; nt < 2; nt++)
                    acc[mt][nt] = __builtin_amdgcn_mfma_f32_16x16x32_f16(aF[mt], bF[nt], acc[mt][nt], 0, 0, 0);
        }
        __builtin_amdgcn_s_setprio(0);
        BAR_REL();
    }

    if (REDUCE == 0) {
        f16* Ob = Hout + (size_t)b * (N_ * H_);
        #pragma unroll
        for (int mt = 0; mt < 4; mt++) {
            int node = wm * 64 + mt * 16 + quad * 4;
            #pragma unroll
            for (int nt = 0; nt < 2; nt++) {
                int hg = hc * 128 + wn * 32 + nt * 16 + ln15;
                #pragma unroll
                for (int rr = 0; rr < 4; rr++) {
                    float v = acc[mt][nt][rr];
                    v = v > 0.f ? v : 0.f;
                    Ob[(size_t)(node + rr) * H_ + hg] = (f16)v;
                }
            }
        }
    } else {
        // node-sum readout: block covers ALL 256 nodes -> gp[b][hc*128 + c]
        float part[2];
        #pragma unroll
        for (int nt = 0; nt < 2; nt++) {
            float s = 0.f;
            #pragma unroll
            for (int mt = 0; mt < 4; mt++)
                #pragma unroll
                for (int rr = 0; rr < 4; rr++) {
                    float v = acc[mt][nt][rr];
                    s += (v > 0.f ? v : 0.f);
                }
            s += __shfl_down(s, 32, 64);
            s += __shfl_down(s, 16, 64);
            part[nt] = s;                            // valid on quad==0 lanes
        }
        __syncthreads();                             // LDS dead; reuse As as scratch
        float* red = (float*)&As[0][0];              // 16 waves x 32 cols
        if (quad == 0) {
            #pragma unroll
            for (int nt = 0; nt < 2; nt++)
                red[wave * 32 + nt * 16 + ln15] = part[nt];
        }
        __syncthreads();
        if (tid < 128) {
            int wnl = tid >> 5, cl = tid & 31;       // h = wnl*32 + cl
            float g = red[(0 * 4 + wnl) * 32 + cl] + red[(1 * 4 + wnl) * 32 + cl]
                    + red[(2 * 4 + wnl) * 32 + cl] + red[(3 * 4 + wnl) * 32 + cl];
            gp[(size_t)b * H_ + hc * 128 + tid] = g;
        }
    }
}

// ---------------------------------------------------------------------------
// k_logits: logits[b] = (gp[b]/N) @ fcw + fcb.  grid B_ x 256.
__global__ __launch_bounds__(256) void k_logits(const float* __restrict__ gp,
                                                const float* __restrict__ fcw,
                                                const float* __restrict__ fcb,
                                                float* __restrict__ out) {
    int b = blockIdx.x, tid = threadIdx.x;
    const float* g = gp + (size_t)b * H_;
    float g0 = g[tid];
    float g1 = g[tid + 256];
    float p0 = g0 * fcw[tid * 2 + 0] + g1 * fcw[(tid + 256) * 2 + 0];
    float p1 = g0 * fcw[tid * 2 + 1] + g1 * fcw[(tid + 256) * 2 + 1];
    for (int off = 32; off; off >>= 1) {
        p0 += __shfl_down(p0, off, 64);
        p1 += __shfl_down(p1, off, 64);
    }
    __shared__ float r0[4], r1[4];
    int lane = tid & 63, w = tid >> 6;
    if (lane == 0) { r0[w] = p0; r1[w] = p1; }
    __syncthreads();
    const float inv = 1.0f / N_;
    if (tid == 0) out[b * 2 + 0] = (r0[0] + r0[1] + r0[2] + r0[3]) * inv + fcb[0];
    if (tid == 1) out[b * 2 + 1] = (r1[0] + r1[1] + r1[2] + r1[3]) * inv + fcb[1];
}

// ---------------------------------------------------------------------------
extern "C" void kernel_launch(void* const* d_in, const int* in_sizes, int n_in,
                              void* d_out, int out_size, void* d_ws, size_t ws_size,
                              hipStream_t stream) {
    const float* z   = (const float*)d_in[0];
    const float* ne  = (const float*)d_in[1];
    const float* w1  = (const float*)d_in[2];
    const float* b1  = (const float*)d_in[3];
    const float* w2  = (const float*)d_in[4];
    const float* b2  = (const float*)d_in[5];
    const float* w3  = (const float*)d_in[6];
    const float* b3  = (const float*)d_in[7];
    const float* fcw = (const float*)d_in[8];
    const float* fcb = (const float*)d_in[9];
    float* out = (float*)d_out;

    char* ws = (char*)d_ws;
    f16*   T     = (f16*)(ws + 0);            // 67,108,864 (T2/T3 intermediate)
    f16*   nA    = (f16*)(ws + 67108864);     // 33,554,432
    f16*   Hh    = (f16*)(ws + 100663296);    // 67,108,864 (H1)
    float* gpart = (float*)(ws + 100663296);  //    524,288 (alias Hh, H1 dead after F2)
    f16*   XW1t  = (f16*)(ws + 167772160);    //    262,144
    f16*   w2t   = (f16*)(ws + 168034304);    //    524,288
    f16*   w3t   = (f16*)(ws + 168558592);    //    524,288

    // Fused sigmoid/symmetrize/normalize: z -> nA directly (S never hits HBM)
    k_fsum<<<256, 512, 0, stream>>>(z, nA);
    k_prep<<<2560, 256, 0, stream>>>(ne, w1, b1, w2, w3, XW1t, w2t, w3t);

    // Layer 1: H1 = relu(nA @ XW1)
    k_gemm<256, 0><<<2048, 256, 0, stream>>>(nA, 65536, XW1t, 0, Hh, nullptr, nullptr);
    // Layer 2 fused: H2 = relu(nA @ (H1 @ w2 + b2))   (U never touches HBM)
    k_fused<0><<<1024, 1024, 0, stream>>>(Hh, w2t, b2, nA, T, nullptr);
    // Layer 3 fused + readout: gp[b][h] = sum_i relu(nA @ (H2 @ w3 + b3))[i][h]
    k_fused<1><<<1024, 1024, 0, stream>>>(T, w3t, b3, nA, nullptr, gpart);

    k_logits<<<B_, 256, 0, stream>>>(gpart, fcw, fcb, out);
}